// Round 5
// baseline (198.291 us; speedup 1.0000x reference)
//
#include <hip/hip_runtime.h>
#include <math.h>

// Problem constants
#define NQ   65536
#define H    32
#define IN   64
#define OUTC 64
#define K    15
#define QB   16          // queries per block
#define S_XN 68          // xn row stride (bf16 elems), b64-aligned, conflict-free
#define S_WT 36          // wT row stride (18 mod 32 dword stride -> spread)
#define AK   68          // Awt k_kp stride (write: 2 lanes/bank uniform = free)
#define AROW 1020        // Awt per-query row stride (510 dw = 30 mod 32 -> 16 banks)
#define INV_EXT (1.0f / 0.048f)

// d_ws layout (bytes)
#define OFF_PSUM  131072                       // psum2 [2][64][64] float = 32 KB
#define OFF_XBF   163840                       // x in bf16: 8 MB
#define NEED_BF16 (OFF_XBF + (size_t)NQ * IN * 2)

typedef __attribute__((ext_vector_type(8))) short short8;
typedef __attribute__((ext_vector_type(4))) short short4v;
typedef __attribute__((ext_vector_type(4))) float float4v;

// round-to-nearest (ties up): 2 VALU ops
static __device__ __forceinline__ unsigned short f2bf(float f) {
    return (unsigned short)((__float_as_uint(f) + 0x8000u) >> 16);
}
static __device__ __forceinline__ unsigned pk2(float a, float b) {
    return (__float_as_uint(a) + 0x8000u) >> 16 |
           ((__float_as_uint(b) + 0x8000u) & 0xFFFF0000u);
}

// ---------------------------------------------------------------------------
// Prep: blocks [0,4096): x fp32 -> bf16 (coalesced).
//       blocks [4096,4336): W repack -> stage-2 B-frag dump order.
//       block 4336: zero psum2 (32 KB).
// ---------------------------------------------------------------------------
__global__ __launch_bounds__(256) void prep_all(
    const float* __restrict__ W, const float* __restrict__ x,
    short* __restrict__ Bfrag, unsigned short* __restrict__ xbf,
    float* __restrict__ psum2, int do_x)
{
    const int b = blockIdx.x;
    if (b < 4096) {
        if (do_x) {
            const int t = b * 256 + threadIdx.x;      // float4 index
            const float4 v = ((const float4*)x)[t];
            uint2 p; p.x = pk2(v.x, v.y); p.y = pk2(v.z, v.w);
            ((uint2*)xbf)[t] = p;
        }
    } else if (b < 4336) {
        const int t2 = (b - 4096) * 256 + threadIdx.x;   // flat W index, coalesced
        const int o  = t2 & 63;
        const int i  = (t2 >> 6) & 63;
        const int kq = t2 >> 12;                          // 0..14
        const int t  = kq * 2 + (i >> 5);
        const int lane = ((i >> 3) & 3) * 16 + (o & 15);
        const int v  = o >> 4;
        const int j  = i & 7;
        Bfrag[((v * 30 + t) * 64 + lane) * 8 + j] = (short)f2bf(W[t2]);
    } else {
        float4 z = {0.f, 0.f, 0.f, 0.f};
#pragma unroll
        for (int i = 0; i < 8; ++i)
            ((float4*)psum2)[threadIdx.x + 256 * i] = z;   // 8192 floats
    }
}

// ---------------------------------------------------------------------------
// Main: fused KPConv via dual MFMA + BN atomic partials in epilogue.
// LDS 32640 B -> 5 blocks/CU. Phase1: xn[4][32][68] + wT[4][16][36];
// phase2: Awt[16][1020] (union).
// ---------------------------------------------------------------------------
template<bool BFX>
__global__ __launch_bounds__(256, 5) void kpconv_mfma(
    const float* __restrict__ x, const unsigned short* __restrict__ xbf,
    const float* __restrict__ qp, const float* __restrict__ sp,
    const int* __restrict__ inds, const float* __restrict__ kp,
    const short* __restrict__ Bfrag, float* __restrict__ out_raw,
    float* __restrict__ psum2)
{
    __shared__ __align__(16) short lds[16320];            // 32640 B
    short* xn  = lds;                                     // [4][32][S_XN] = 8704
    short* wT  = lds + 8704;                              // [4][16][S_WT] = 2304
    short* Awt = lds;                                     // phase 2: 16320

    const int tid  = threadIdx.x;
    const int lane = tid & 63;
    const int wv   = tid >> 6;
    const int quad = lane >> 4;
    const int ml   = lane & 15;
    const int q0   = blockIdx.x * QB;

    float4v frag[QB];
#pragma unroll
    for (int qg = 0; qg < QB; ++qg) frag[qg] = (float4v){0.f, 0.f, 0.f, 0.f};

    for (int b = 0; b < 4; ++b) {
        // ---- issue gather loads for this wave's staged query ----
        const int ibase = (q0 + 4 * b + wv) * H;
        short4v xv[8];
        float4  xf[8];
#pragma unroll
        for (int j = 0; j < 8; ++j) {
            const int id = inds[ibase + j * 4 + quad];     // quad-uniform bcast
            if (BFX)
                xv[j] = *(const short4v*)((const short*)xbf + id * IN + ml * 4);
            else
                xf[j] = *(const float4*)(x + id * IN + ml * 4);
        }

        // ---- stage A (VALU) runs in the gather-load latency shadow ----
        {
            const int h = lane >> 1, half = lane & 1;
            const int nq_ = q0 + 4 * b + wv;
            const int idA = inds[nq_ * H + h];
            const float dx = sp[idA * 3 + 0] - qp[nq_ * 3 + 0];
            const float dy = sp[idA * 3 + 1] - qp[nq_ * 3 + 1];
            const float dz = sp[idA * 3 + 2] - qp[nq_ * 3 + 2];
#pragma unroll
            for (int kk = 0; kk < 8; ++kk) {
                const int k = half * 8 + kk;
                float wval = 0.f;
                if (k < K) {
                    const float ex = dx - kp[k * 3 + 0];
                    const float ey = dy - kp[k * 3 + 1];
                    const float ez = dz - kp[k * 3 + 2];
                    const float sq = ex * ex + ey * ey + ez * ez;
                    wval = 1.0f - __builtin_amdgcn_sqrtf(sq) * INV_EXT;
                    wval = wval > 0.0f ? wval : 0.0f;
                }
                wT[(wv * 16 + k) * S_WT + h] = (short)f2bf(wval);
            }
        }

        // ---- write gathered rows to xn ----
#pragma unroll
        for (int j = 0; j < 8; ++j) {
            if (BFX) {
                *(short4v*)&xn[(wv * H + j * 4 + quad) * S_XN + ml * 4] = xv[j];
            } else {
                short4v p;
                p[0] = (short)f2bf(xf[j].x); p[1] = (short)f2bf(xf[j].y);
                p[2] = (short)f2bf(xf[j].z); p[3] = (short)f2bf(xf[j].w);
                *(short4v*)&xn[(wv * H + j * 4 + quad) * S_XN + ml * 4] = p;
            }
        }
        __syncthreads();

        // ---- MFMA: 4 queries of this sub-batch, n-tile = wv ----
#pragma unroll
        for (int ql = 0; ql < 4; ++ql) {
            const int qg = 4 * b + ql;
            const int arow = (ql * 16 + ml) * S_WT + quad * 8;
            const short4v alo = *(const short4v*)&wT[arow];
            const short4v ahi = *(const short4v*)&wT[arow + 4];
            short8 a;
#pragma unroll
            for (int e = 0; e < 4; ++e) { a[e] = alo[e]; a[e + 4] = ahi[e]; }
            short8 bb;
#pragma unroll
            for (int j = 0; j < 8; ++j)
                bb[j] = xn[(ql * H + quad * 8 + j) * S_XN + wv * 16 + ml];
            frag[qg] = __builtin_amdgcn_mfma_f32_16x16x32_bf16(a, bb, frag[qg], 0, 0, 0);
        }
        __syncthreads();
    }

    // ---- Round trip: C-frags -> Awt (stage-2 A layout, bf16) ----
#pragma unroll
    for (int qg = 0; qg < QB; ++qg) {
#pragma unroll
        for (int r = 0; r < 4; ++r) {
            const int kq = quad * 4 + r;
            if (kq < K)
                Awt[qg * AROW + kq * AK + wv * 16 + ml] = (short)f2bf(frag[qg][r]);
        }
    }
    __syncthreads();

    // ---- Stage 2: out[q][o] = sum_{k'} Awt[q][k'] * W'[k'][o] ----
    float4v acc = (float4v){0.f, 0.f, 0.f, 0.f};
    const short* bptr = Bfrag + (wv * 30) * 512 + lane * 8;
#pragma unroll 2
    for (int t = 0; t < 30; ++t) {
        const int abase = ml * AROW + (t >> 1) * AK + (t & 1) * 32 + quad * 8;
        const short4v alo = *(const short4v*)&Awt[abase];
        const short4v ahi = *(const short4v*)&Awt[abase + 4];
        short8 a;
#pragma unroll
        for (int e = 0; e < 4; ++e) { a[e] = alo[e]; a[e + 4] = ahi[e]; }
        const short8 bb = *(const short8*)(bptr + t * 512);
        acc = __builtin_amdgcn_mfma_f32_16x16x32_bf16(a, bb, acc, 0, 0, 0);
    }

    // ---- Epilogue: raw out + BN channel partials (atomic, 64 slots) ----
    float s = 0.f, s2 = 0.f;
#pragma unroll
    for (int r = 0; r < 4; ++r) {
        const float v = acc[r];
        out_raw[(q0 + quad * 4 + r) * OUTC + wv * 16 + ml] = v;
        s += v; s2 += v * v;
    }
    s  += __shfl_xor(s, 16, 64);  s  += __shfl_xor(s, 32, 64);
    s2 += __shfl_xor(s2, 16, 64); s2 += __shfl_xor(s2, 32, 64);
    if (quad == 0) {
        const int c = wv * 16 + ml;
        const int slot = blockIdx.x & 63;
        atomicAdd(&psum2[slot * 64 + c], s);
        atomicAdd(&psum2[4096 + slot * 64 + c], s2);
    }
}

// ---------------------------------------------------------------------------
// BN stats (redundant per block, 32 KB L2-broadcast) + apply + LeakyReLU
// ---------------------------------------------------------------------------
__global__ __launch_bounds__(256) void bn_apply(
    float* __restrict__ out, const float* __restrict__ psum2,
    const float* __restrict__ gamma, const float* __restrict__ beta)
{
    __shared__ float red[8][64];
    __shared__ float sc[64], sh[64];
    const int c = threadIdx.x & 63;
    const int g = threadIdx.x >> 6;
    float s = 0.f, q2 = 0.f;
#pragma unroll
    for (int i = 0; i < 16; ++i) {
        const int sl = g * 16 + i;
        s  += psum2[sl * 64 + c];
        q2 += psum2[4096 + sl * 64 + c];
    }
    red[g][c] = s; red[4 + g][c] = q2;
    __syncthreads();
    if (g == 0) {
        s  = red[0][c] + red[1][c] + red[2][c] + red[3][c];
        q2 = red[4][c] + red[5][c] + red[6][c] + red[7][c];
        const float mean = s * (1.0f / (float)NQ);
        const float var  = q2 * (1.0f / (float)NQ) - mean * mean;
        const float scale = gamma[c] / sqrtf(var + 1e-5f);
        sc[c] = scale;
        sh[c] = beta[c] - mean * scale;
    }
    __syncthreads();
    const int idx = blockIdx.x * 256 + threadIdx.x;
#pragma unroll
    for (int it = 0; it < 4; ++it) {
        const int e = idx + it * 262144;
        float4 v = ((const float4*)out)[e];
        const int cg = (e & 15) * 4;
        float4 r;
        r.x = v.x * sc[cg + 0] + sh[cg + 0];
        r.y = v.y * sc[cg + 1] + sh[cg + 1];
        r.z = v.z * sc[cg + 2] + sh[cg + 2];
        r.w = v.w * sc[cg + 3] + sh[cg + 3];
        r.x = r.x >= 0.0f ? r.x : 0.1f * r.x;
        r.y = r.y >= 0.0f ? r.y : 0.1f * r.y;
        r.z = r.z >= 0.0f ? r.z : 0.1f * r.z;
        r.w = r.w >= 0.0f ? r.w : 0.1f * r.w;
        ((float4*)out)[e] = r;
    }
}

// ---------------------------------------------------------------------------
extern "C" void kernel_launch(void* const* d_in, const int* in_sizes, int n_in,
                              void* d_out, int out_size, void* d_ws, size_t ws_size,
                              hipStream_t stream)
{
    (void)in_sizes; (void)n_in; (void)out_size;
    const float* x     = (const float*)d_in[0];
    const float* qp    = (const float*)d_in[1];
    const float* sp    = (const float*)d_in[2];
    const int*   inds  = (const int*)d_in[3];
    const float* kp    = (const float*)d_in[4];
    const float* W     = (const float*)d_in[5];
    const float* gamma = (const float*)d_in[6];
    const float* beta  = (const float*)d_in[7];
    float* out = (float*)d_out;

    short*          Bfrag = (short*)d_ws;
    float*          psum2 = (float*)((char*)d_ws + OFF_PSUM);
    unsigned short* xbf   = (unsigned short*)((char*)d_ws + OFF_XBF);

    const int use_bf = (ws_size >= NEED_BF16) ? 1 : 0;

    prep_all<<<4337, 256, 0, stream>>>(W, x, Bfrag, xbf, psum2, use_bf);
    if (use_bf)
        kpconv_mfma<true><<<NQ / QB, 256, 0, stream>>>(x, xbf, qp, sp, inds, kp, Bfrag, out, psum2);
    else
        kpconv_mfma<false><<<NQ / QB, 256, 0, stream>>>(x, xbf, qp, sp, inds, kp, Bfrag, out, psum2);
    bn_apply<<<1024, 256, 0, stream>>>(out, psum2, gamma, beta);
}